// Round 1
// baseline (537.035 us; speedup 1.0000x reference)
//
#include <hip/hip_runtime.h>
#include <hip/hip_bf16.h>

using bf16 = __hip_bfloat16;
typedef __bf16 bf16x8v __attribute__((ext_vector_type(8)));
typedef float f32x4 __attribute__((ext_vector_type(4)));

static constexpr int SEQ = 2048;
static constexpr int DMODEL = 2048;
static constexpr int NHEADS = 16;
static constexpr int DQKC = 192;   // nope 128 + rope 64
static constexpr int DVC = 128;
static constexpr int DQC = 1536;
static constexpr int DCC = 512;
static constexpr int HQK = NHEADS * DQKC;  // 3072
static constexpr int HV = NHEADS * DVC;    // 2048

typedef __attribute__((address_space(1))) const void* gas_ptr;
typedef __attribute__((address_space(3))) void* las_ptr;

__device__ __forceinline__ void g2l16(const void* g, void* l) {
  __builtin_amdgcn_global_load_lds((gas_ptr)g, (las_ptr)l, 16, 0, 0);
}

// C[M,N] = alpha * A[M,K] @ Bt[N,K]^T.  Optional z-batch (head) strides and
// causal tile skip (skip whole 128x128 tiles with col-tile > row-tile).
// M,N multiples of 128 via grid; K multiple of 32.
__global__ __launch_bounds__(256) void gemm_bt(
    const bf16* __restrict__ A, int lda, long strideAz,
    const bf16* __restrict__ Bt, int ldb, long strideBz,
    void* __restrict__ Cv, int ldc, long strideCz,
    int K, float alpha, int c_fp32, int causal)
{
  if (causal && blockIdx.x > blockIdx.y) return;
  __shared__ __align__(16) bf16 As[128 * 32];
  __shared__ __align__(16) bf16 Bs[128 * 32];
  const int z = blockIdx.z;
  A += (long)z * strideAz;
  Bt += (long)z * strideBz;
  const int tid = threadIdx.x;
  const int wv = tid >> 6;
  const int lane = tid & 63;
  const int wm = (wv >> 1) * 64, wn = (wv & 1) * 64;
  const long tm = (long)blockIdx.y * 128, tn = (long)blockIdx.x * 128;
  const int r16 = lane >> 2;          // row within 16-row staging chunk
  const int c8 = (lane & 3) * 8;      // col offset (8 bf16 = 16B)
  const bf16* Ag = A + (tm + wv * 32 + r16) * lda + c8;
  const bf16* Bg = Bt + (tn + wv * 32 + r16) * ldb + c8;
  bf16* lA0 = &As[(wv * 32) * 32];    // HW adds lane*16B -> row-major 128x32
  bf16* lA1 = &As[(wv * 32 + 16) * 32];
  bf16* lB0 = &Bs[(wv * 32) * 32];
  bf16* lB1 = &Bs[(wv * 32 + 16) * 32];
  const int m0 = lane & 15;
  const int q8 = (lane >> 4) * 8;
  f32x4 acc[4][4] = {};
  for (int bk = 0; bk < K; bk += 32) {
    g2l16(Ag + bk, lA0);
    g2l16(Ag + bk + 16 * (long)lda, lA1);
    g2l16(Bg + bk, lB0);
    g2l16(Bg + bk + 16 * (long)ldb, lB1);
    __syncthreads();   // drains vmcnt before barrier (compiler-inserted)
    bf16x8v af[4], bfv[4];
#pragma unroll
    for (int i = 0; i < 4; i++)
      af[i] = *reinterpret_cast<const bf16x8v*>(&As[(wm + i * 16 + m0) * 32 + q8]);
#pragma unroll
    for (int i = 0; i < 4; i++)
      bfv[i] = *reinterpret_cast<const bf16x8v*>(&Bs[(wn + i * 16 + m0) * 32 + q8]);
#pragma unroll
    for (int mi = 0; mi < 4; mi++)
#pragma unroll
      for (int ni = 0; ni < 4; ni++)
        acc[mi][ni] = __builtin_amdgcn_mfma_f32_16x16x32_bf16(af[mi], bfv[ni], acc[mi][ni], 0, 0, 0);
    __syncthreads();
  }
  // C/D layout (verified m89/m91): col = lane&15, row = (lane>>4)*4 + reg
  const int q4 = (lane >> 4) * 4;
  float* Cf = (float*)Cv;
  bf16* Cb = (bf16*)Cv;
  const long zc = (long)z * strideCz;
#pragma unroll
  for (int mi = 0; mi < 4; mi++) {
#pragma unroll
    for (int r = 0; r < 4; r++) {
      const long row = tm + wm + mi * 16 + q4 + r;
#pragma unroll
      for (int ni = 0; ni < 4; ni++) {
        const long idx = zc + row * ldc + tn + wn + ni * 16 + m0;
        const float v = acc[mi][ni][r] * alpha;
        if (c_fp32) Cf[idx] = v;
        else Cb[idx] = __float2bfloat16(v);
      }
    }
  }
}

__device__ __forceinline__ float tofl(float x) { return x; }
__device__ __forceinline__ float tofl(bf16 x) { return __bfloat162float(x); }

// out[C x R] = cast_bf16(in[R x C]^T). block (32,8), grid (C/32, R/32)
template <typename TIN>
__global__ __launch_bounds__(256) void transpose_cast(const TIN* __restrict__ in,
                                                      bf16* __restrict__ out,
                                                      int R, int C) {
  __shared__ float t[32][33];
  const int bx = blockIdx.x * 32, by = blockIdx.y * 32;
  const int tx = threadIdx.x, ty = threadIdx.y;
#pragma unroll
  for (int j = 0; j < 32; j += 8)
    t[ty + j][tx] = tofl(in[(long)(by + ty + j) * C + bx + tx]);
  __syncthreads();
#pragma unroll
  for (int j = 0; j < 32; j += 8)
    out[(long)(bx + ty + j) * R + by + tx] = __float2bfloat16(t[tx][ty + j]);
}

__global__ __launch_bounds__(256) void cast_f32_bf16(const float* __restrict__ in,
                                                     bf16* __restrict__ out, int n4) {
  int i = blockIdx.x * 256 + threadIdx.x;
  if (i < n4) {
    const float4 v = ((const float4*)in)[i];
    out[i * 4 + 0] = __float2bfloat16(v.x);
    out[i * 4 + 1] = __float2bfloat16(v.y);
    out[i * 4 + 2] = __float2bfloat16(v.z);
    out[i * 4 + 3] = __float2bfloat16(v.w);
  }
}

// Each thread owns one rotation pair (i, i+32) of one (l,h): reads both
// partners before writing either -> no in-place race.
__global__ __launch_bounds__(256) void rope_qk(bf16* __restrict__ q, bf16* __restrict__ k) {
  const int idx = blockIdx.x * 256 + threadIdx.x;  // SEQ*NHEADS*32 threads
  const int i = idx & 31;
  const int h = (idx >> 5) & 15;
  const int l = idx >> 9;
  const float inv = powf(10000.f, -(float)i * (1.f / 32.f));
  float s, c;
  sincosf((float)l * inv, &s, &c);
  const long base = (long)l * HQK + h * DQKC + 128;
  {
    float x0 = __bfloat162float(q[base + i]);
    float x1 = __bfloat162float(q[base + i + 32]);
    q[base + i] = __float2bfloat16(x0 * c - x1 * s);
    q[base + i + 32] = __float2bfloat16(x1 * c + x0 * s);
  }
  {
    float x0 = __bfloat162float(k[base + i]);
    float x1 = __bfloat162float(k[base + i + 32]);
    k[base + i] = __float2bfloat16(x0 * c - x1 * s);
    k[base + i + 32] = __float2bfloat16(x1 * c + x0 * s);
  }
}

// In-place causal softmax on bf16 scores rows (scale already folded into q).
// grid (SEQ, nz), block 256; each thread owns 8 columns.
__global__ __launch_bounds__(256) void softmax_causal(bf16* __restrict__ SP) {
  const int q = blockIdx.x;
  bf16* row = SP + (long)blockIdx.y * SEQ * SEQ + (long)q * SEQ;
  const int tid = threadIdx.x;
  float e[8];
  float m = -1e30f;
#pragma unroll
  for (int it = 0; it < 8; it++) {
    const int kx = tid + it * 256;
    const float v = (kx <= q) ? __bfloat162float(row[kx]) : -1e30f;
    e[it] = v;
    m = fmaxf(m, v);
  }
  for (int o = 32; o > 0; o >>= 1) m = fmaxf(m, __shfl_down(m, o, 64));
  __shared__ float sm[4], ss[4];
  const int wv = tid >> 6, ln = tid & 63;
  if (ln == 0) sm[wv] = m;
  __syncthreads();
  m = fmaxf(fmaxf(sm[0], sm[1]), fmaxf(sm[2], sm[3]));
  float sum = 0.f;
#pragma unroll
  for (int it = 0; it < 8; it++) {
    const float v = (e[it] > -1e29f) ? expf(e[it] - m) : 0.f;
    e[it] = v;
    sum += v;
  }
  for (int o = 32; o > 0; o >>= 1) sum += __shfl_down(sum, o, 64);
  if (ln == 0) ss[wv] = sum;
  __syncthreads();
  sum = ss[0] + ss[1] + ss[2] + ss[3];
  const float r = 1.f / sum;
#pragma unroll
  for (int it = 0; it < 8; it++) row[tid + it * 256] = __float2bfloat16(e[it] * r);
}

extern "C" void kernel_launch(void* const* d_in, const int* in_sizes, int n_in,
                              void* d_out, int out_size, void* d_ws, size_t ws_size,
                              hipStream_t stream) {
  const float* hs      = (const float*)d_in[0];
  // d_in[1] attention_mask: exact causal mask; applied analytically.
  const float* Wq_down = (const float*)d_in[2];
  const float* Wq_up   = (const float*)d_in[3];
  const float* Wkv_down= (const float*)d_in[4];
  const float* Wk_up   = (const float*)d_in[5];
  const float* Wv_up   = (const float*)d_in[6];
  const float* Wo      = (const float*)d_in[7];

  char* p = (char*)d_ws;
  auto alloc = [&](long elems) {
    bf16* r = (bf16*)p;
    p += ((elems * 2 + 255) / 256) * 256;
    return r;
  };
  bf16* hsb   = alloc((long)SEQ * DMODEL);
  bf16* WqdT  = alloc((long)DQC * DMODEL);
  bf16* WquT  = alloc((long)HQK * DQC);
  bf16* WkvdT = alloc((long)DCC * DMODEL);
  bf16* WkuT  = alloc((long)HQK * DCC);
  bf16* WvuT  = alloc((long)HV * DCC);
  bf16* WoT   = alloc((long)DMODEL * HV);
  bf16* qd    = alloc((long)SEQ * DQC);
  bf16* qf    = alloc((long)SEQ * HQK);
  bf16* ckv   = alloc((long)SEQ * DCC);
  bf16* kf    = alloc((long)SEQ * HQK);
  bf16* vf    = alloc((long)SEQ * HV);
  bf16* vT    = alloc((long)HV * SEQ);
  bf16* attn  = alloc((long)SEQ * HV);
  // scores/P buffer: as many heads at once as the workspace allows
  const size_t used = (size_t)(p - (char*)d_ws);
  const size_t avail = ws_size > used ? ws_size - used : 0;
  const size_t perHead = (size_t)SEQ * SEQ * 2;
  int nz = 16;
  while (nz > 1 && (size_t)nz * perHead > avail) nz >>= 1;
  bf16* SP = (bf16*)p;

  const float scale = 0.07216878364870323f;  // 1/sqrt(192), folded into q

  const dim3 b256(256);
  const dim3 tb(32, 8);
  cast_f32_bf16<<<dim3(SEQ * DMODEL / 4 / 256), b256, 0, stream>>>(hs, hsb, SEQ * DMODEL / 4);
  transpose_cast<float><<<dim3(DQC / 32, DMODEL / 32), tb, 0, stream>>>(Wq_down, WqdT, DMODEL, DQC);
  transpose_cast<float><<<dim3(HQK / 32, DQC / 32), tb, 0, stream>>>(Wq_up, WquT, DQC, HQK);
  transpose_cast<float><<<dim3(DCC / 32, DMODEL / 32), tb, 0, stream>>>(Wkv_down, WkvdT, DMODEL, DCC);
  transpose_cast<float><<<dim3(HQK / 32, DCC / 32), tb, 0, stream>>>(Wk_up, WkuT, DCC, HQK);
  transpose_cast<float><<<dim3(HV / 32, DCC / 32), tb, 0, stream>>>(Wv_up, WvuT, DCC, HV);
  transpose_cast<float><<<dim3(DMODEL / 32, HV / 32), tb, 0, stream>>>(Wo, WoT, HV, DMODEL);

  // projections
  gemm_bt<<<dim3(DQC / 128, SEQ / 128), b256, 0, stream>>>(
      hsb, DMODEL, 0, WqdT, DMODEL, 0, qd, DQC, 0, DMODEL, 1.f, 0, 0);
  gemm_bt<<<dim3(HQK / 128, SEQ / 128), b256, 0, stream>>>(
      qd, DQC, 0, WquT, DQC, 0, qf, HQK, 0, DQC, scale, 0, 0);
  gemm_bt<<<dim3(DCC / 128, SEQ / 128), b256, 0, stream>>>(
      hsb, DMODEL, 0, WkvdT, DMODEL, 0, ckv, DCC, 0, DMODEL, 1.f, 0, 0);
  gemm_bt<<<dim3(HQK / 128, SEQ / 128), b256, 0, stream>>>(
      ckv, DCC, 0, WkuT, DCC, 0, kf, HQK, 0, DCC, 1.f, 0, 0);
  gemm_bt<<<dim3(HV / 128, SEQ / 128), b256, 0, stream>>>(
      ckv, DCC, 0, WvuT, DCC, 0, vf, HV, 0, DCC, 1.f, 0, 0);

  rope_qk<<<dim3(SEQ * NHEADS * 32 / 256), b256, 0, stream>>>(qf, kf);
  transpose_cast<bf16><<<dim3(HV / 32, SEQ / 32), tb, 0, stream>>>(vf, vT, SEQ, HV);

  // attention, nz heads per pass
  for (int h0 = 0; h0 < NHEADS; h0 += nz) {
    gemm_bt<<<dim3(SEQ / 128, SEQ / 128, nz), b256, 0, stream>>>(
        qf + h0 * DQKC, HQK, DQKC,
        kf + h0 * DQKC, HQK, DQKC,
        SP, SEQ, (long)SEQ * SEQ, DQKC, 1.f, 0, /*causal=*/1);
    softmax_causal<<<dim3(SEQ, nz), b256, 0, stream>>>(SP);
    gemm_bt<<<dim3(DVC / 128, SEQ / 128, nz), b256, 0, stream>>>(
        SP, SEQ, (long)SEQ * SEQ,
        vT + (long)h0 * DVC * SEQ, SEQ, (long)DVC * SEQ,
        attn + h0 * DVC, HV, DVC, SEQ, 1.f, 0, 0);
  }

  // output projection (fp32 out)
  gemm_bt<<<dim3(DMODEL / 128, SEQ / 128), b256, 0, stream>>>(
      attn, HV, 0, WoT, HV, 0, d_out, DMODEL, 0, HV, 1.f, 1, 0);
}

// Round 2
// 452.744 us; speedup vs baseline: 1.1862x; 1.1862x over previous
//
#include <hip/hip_runtime.h>
#include <hip/hip_bf16.h>

using bf16 = __hip_bfloat16;
typedef __bf16 bf16x8v __attribute__((ext_vector_type(8)));
typedef float f32x4 __attribute__((ext_vector_type(4)));

static constexpr int SEQ = 2048;
static constexpr int DMODEL = 2048;
static constexpr int NHEADS = 16;
static constexpr int DQKC = 192;   // nope 128 + rope 64
static constexpr int DVC = 128;
static constexpr int DQC = 1536;
static constexpr int DCC = 512;
static constexpr int HQK = NHEADS * DQKC;  // 3072
static constexpr int HV = NHEADS * DVC;    // 2048
static constexpr int NKV = HQK + HV;       // 5120 (fused k_up|v_up output width)
static constexpr int NDOWN = DQC + DCC;    // 2048 (fused q_down|kv_down width)

typedef __attribute__((address_space(1))) const void* gas_ptr;
typedef __attribute__((address_space(3))) void* las_ptr;

__device__ __forceinline__ void g2l16(const void* g, void* l) {
  __builtin_amdgcn_global_load_lds((gas_ptr)g, (las_ptr)l, 16, 0, 0);
}

// C[M,N] = alpha * A[M,K] @ Bt[N,K]^T.  Optional z-batch (head) strides.
// causal=1: skip tiles with col-tile > row-tile (scores GEMM).
// causal=2: cap K at (row-tile+1)*128 (PV GEMM; P is zero beyond the diag).
__global__ __launch_bounds__(256) void gemm_bt(
    const bf16* __restrict__ A, int lda, long strideAz,
    const bf16* __restrict__ Bt, int ldb, long strideBz,
    void* __restrict__ Cv, int ldc, long strideCz,
    int K, float alpha, int c_fp32, int causal)
{
  if (causal == 1 && blockIdx.x > blockIdx.y) return;
  int Keff = K;
  if (causal == 2) Keff = min(K, ((int)blockIdx.y + 1) * 128);
  __shared__ __align__(16) bf16 As[128 * 32];
  __shared__ __align__(16) bf16 Bs[128 * 32];
  const int z = blockIdx.z;
  A += (long)z * strideAz;
  Bt += (long)z * strideBz;
  const int tid = threadIdx.x;
  const int wv = tid >> 6;
  const int lane = tid & 63;
  const int wm = (wv >> 1) * 64, wn = (wv & 1) * 64;
  const long tm = (long)blockIdx.y * 128, tn = (long)blockIdx.x * 128;
  const int r16 = lane >> 2;          // row within 16-row staging chunk
  const int c8 = (lane & 3) * 8;      // col offset (8 bf16 = 16B)
  const bf16* Ag = A + (tm + wv * 32 + r16) * lda + c8;
  const bf16* Bg = Bt + (tn + wv * 32 + r16) * ldb + c8;
  bf16* lA0 = &As[(wv * 32) * 32];    // HW adds lane*16B -> row-major 128x32
  bf16* lA1 = &As[(wv * 32 + 16) * 32];
  bf16* lB0 = &Bs[(wv * 32) * 32];
  bf16* lB1 = &Bs[(wv * 32 + 16) * 32];
  const int m0 = lane & 15;
  const int q8 = (lane >> 4) * 8;
  f32x4 acc[4][4] = {};
  for (int bk = 0; bk < Keff; bk += 32) {
    g2l16(Ag + bk, lA0);
    g2l16(Ag + bk + 16 * (long)lda, lA1);
    g2l16(Bg + bk, lB0);
    g2l16(Bg + bk + 16 * (long)ldb, lB1);
    __syncthreads();
    bf16x8v af[4], bfv[4];
#pragma unroll
    for (int i = 0; i < 4; i++)
      af[i] = *reinterpret_cast<const bf16x8v*>(&As[(wm + i * 16 + m0) * 32 + q8]);
#pragma unroll
    for (int i = 0; i < 4; i++)
      bfv[i] = *reinterpret_cast<const bf16x8v*>(&Bs[(wn + i * 16 + m0) * 32 + q8]);
#pragma unroll
    for (int mi = 0; mi < 4; mi++)
#pragma unroll
      for (int ni = 0; ni < 4; ni++)
        acc[mi][ni] = __builtin_amdgcn_mfma_f32_16x16x32_bf16(af[mi], bfv[ni], acc[mi][ni], 0, 0, 0);
    __syncthreads();
  }
  // C/D layout (verified m89/m91): col = lane&15, row = (lane>>4)*4 + reg
  const int q4 = (lane >> 4) * 4;
  float* Cf = (float*)Cv;
  bf16* Cb = (bf16*)Cv;
  const long zc = (long)z * strideCz;
#pragma unroll
  for (int mi = 0; mi < 4; mi++) {
#pragma unroll
    for (int r = 0; r < 4; r++) {
      const long row = tm + wm + mi * 16 + q4 + r;
#pragma unroll
      for (int ni = 0; ni < 4; ni++) {
        const long idx = zc + row * ldc + tn + wn + ni * 16 + m0;
        const float v = acc[mi][ni][r] * alpha;
        if (c_fp32) Cf[idx] = v;
        else Cb[idx] = __float2bfloat16(v);
      }
    }
  }
}

__device__ __forceinline__ float tofl(float x) { return x; }
__device__ __forceinline__ float tofl(bf16 x) { return __bfloat162float(x); }

// out[C x R] = cast_bf16(in[R x C]^T), with explicit in/out row strides.
// block (32,8), grid (C/32, R/32)
template <typename TIN>
__global__ __launch_bounds__(256) void transpose_cast(const TIN* __restrict__ in,
                                                      bf16* __restrict__ out,
                                                      int inStride, int outStride) {
  __shared__ float t[32][33];
  const int bx = blockIdx.x * 32, by = blockIdx.y * 32;
  const int tx = threadIdx.x, ty = threadIdx.y;
#pragma unroll
  for (int j = 0; j < 32; j += 8)
    t[ty + j][tx] = tofl(in[(long)(by + ty + j) * inStride + bx + tx]);
  __syncthreads();
#pragma unroll
  for (int j = 0; j < 32; j += 8)
    out[(long)(bx + ty + j) * outStride + by + tx] = __float2bfloat16(t[tx][ty + j]);
}

__global__ __launch_bounds__(256) void cast_f32_bf16(const float* __restrict__ in,
                                                     bf16* __restrict__ out, int n4) {
  int i = blockIdx.x * 256 + threadIdx.x;
  if (i < n4) {
    const float4 v = ((const float4*)in)[i];
    out[i * 4 + 0] = __float2bfloat16(v.x);
    out[i * 4 + 1] = __float2bfloat16(v.y);
    out[i * 4 + 2] = __float2bfloat16(v.z);
    out[i * 4 + 3] = __float2bfloat16(v.w);
  }
}

// One thread per rotation pair (i, i+32) of one (l,h); q and k have
// different row strides now (k lives inside the fused kv buffer).
__global__ __launch_bounds__(256) void rope_qk(bf16* __restrict__ q, bf16* __restrict__ k) {
  const int idx = blockIdx.x * 256 + threadIdx.x;  // SEQ*NHEADS*32 threads
  const int i = idx & 31;
  const int h = (idx >> 5) & 15;
  const int l = idx >> 9;
  const float inv = powf(10000.f, -(float)i * (1.f / 32.f));
  float s, c;
  sincosf((float)l * inv, &s, &c);
  const long qb = (long)l * HQK + h * DQKC + 128;
  const long kb = (long)l * NKV + h * DQKC + 128;
  {
    float x0 = __bfloat162float(q[qb + i]);
    float x1 = __bfloat162float(q[qb + i + 32]);
    q[qb + i] = __float2bfloat16(x0 * c - x1 * s);
    q[qb + i + 32] = __float2bfloat16(x1 * c + x0 * s);
  }
  {
    float x0 = __bfloat162float(k[kb + i]);
    float x1 = __bfloat162float(k[kb + i + 32]);
    k[kb + i] = __float2bfloat16(x0 * c - x1 * s);
    k[kb + i + 32] = __float2bfloat16(x1 * c + x0 * s);
  }
}

// In-place causal softmax. Row q: columns 0..q get softmax, q+1..cover-1 get
// zeros (cover = next 128 boundary — exactly what the K-limited PV reads).
// Contiguous 8-elem ownership -> one bf16x8 load/store per active thread;
// waves fully beyond q skip compute.
__global__ __launch_bounds__(256) void softmax_causal(bf16* __restrict__ SP) {
  const int q = blockIdx.x;
  bf16* row = SP + (long)blockIdx.y * SEQ * SEQ + (long)q * SEQ;
  const int tid = threadIdx.x;
  const int k0 = tid * 8;
  const int cover = ((q >> 7) + 1) * 128;
  const bool active = (k0 <= q);
  float e[8];
  float m = -1e30f;
  if (active) {
    union { bf16x8v v; unsigned short u[8]; } in;
    in.v = *reinterpret_cast<const bf16x8v*>(row + k0);
#pragma unroll
    for (int j = 0; j < 8; j++) {
      const float v = (k0 + j <= q) ? __uint_as_float((unsigned)in.u[j] << 16) : -1e30f;
      e[j] = v;
      m = fmaxf(m, v);
    }
  } else {
#pragma unroll
    for (int j = 0; j < 8; j++) e[j] = 0.f;
  }
  for (int o = 32; o > 0; o >>= 1) m = fmaxf(m, __shfl_down(m, o, 64));
  __shared__ float sm[4], ss[4];
  const int wv = tid >> 6, ln = tid & 63;
  if (ln == 0) sm[wv] = m;
  __syncthreads();
  m = fmaxf(fmaxf(sm[0], sm[1]), fmaxf(sm[2], sm[3]));
  float sum = 0.f;
  if (active) {
#pragma unroll
    for (int j = 0; j < 8; j++) {
      const float v = (e[j] > -1e29f) ? __expf(e[j] - m) : 0.f;
      e[j] = v;
      sum += v;
    }
  }
  for (int o = 32; o > 0; o >>= 1) sum += __shfl_down(sum, o, 64);
  if (ln == 0) ss[wv] = sum;
  __syncthreads();
  sum = ss[0] + ss[1] + ss[2] + ss[3];
  const float r = 1.f / sum;
  if (k0 < cover) {
    union { bf16x8v v; unsigned short u[8]; } out;
#pragma unroll
    for (int j = 0; j < 8; j++) {
      const bf16 b = __float2bfloat16(e[j] * r);
      out.u[j] = *reinterpret_cast<const unsigned short*>(&b);
    }
    *reinterpret_cast<bf16x8v*>(row + k0) = out.v;
  }
}

extern "C" void kernel_launch(void* const* d_in, const int* in_sizes, int n_in,
                              void* d_out, int out_size, void* d_ws, size_t ws_size,
                              hipStream_t stream) {
  const float* hs      = (const float*)d_in[0];
  // d_in[1] attention_mask: exact causal mask; applied analytically.
  const float* Wq_down = (const float*)d_in[2];
  const float* Wq_up   = (const float*)d_in[3];
  const float* Wkv_down= (const float*)d_in[4];
  const float* Wk_up   = (const float*)d_in[5];
  const float* Wv_up   = (const float*)d_in[6];
  const float* Wo      = (const float*)d_in[7];

  char* p = (char*)d_ws;
  auto alloc = [&](long elems) {
    bf16* r = (bf16*)p;
    p += ((elems * 2 + 255) / 256) * 256;
    return r;
  };
  bf16* hsb   = alloc((long)SEQ * DMODEL);
  bf16* W1T   = alloc((long)NDOWN * DMODEL);   // rows 0..1535 WqdT | 1536.. WkvdT
  bf16* WquT  = alloc((long)HQK * DQC);
  bf16* WkvuT = alloc((long)NKV * DCC);        // rows 0..3071 WkuT | 3072.. WvuT
  bf16* WoT   = alloc((long)DMODEL * HV);
  bf16* qdc   = alloc((long)SEQ * NDOWN);      // cols 0..1535 qd | 1536.. ckv
  bf16* qf    = alloc((long)SEQ * HQK);
  bf16* kvf   = alloc((long)SEQ * NKV);        // cols 0..3071 k | 3072.. v
  bf16* vT    = alloc((long)HV * SEQ);
  bf16* attn  = alloc((long)SEQ * HV);
  const size_t used = (size_t)(p - (char*)d_ws);
  const size_t avail = ws_size > used ? ws_size - used : 0;
  const size_t perHead = (size_t)SEQ * SEQ * 2;
  int nz = 16;
  while (nz > 1 && (size_t)nz * perHead > avail) nz >>= 1;
  bf16* SP = (bf16*)p;

  const float scale = 0.07216878364870323f;  // 1/sqrt(192), folded into q

  const dim3 b256(256);
  const dim3 tb(32, 8);
  cast_f32_bf16<<<dim3(SEQ * DMODEL / 4 / 256), b256, 0, stream>>>(hs, hsb, SEQ * DMODEL / 4);
  transpose_cast<float><<<dim3(DQC / 32, DMODEL / 32), tb, 0, stream>>>(Wq_down, W1T, DQC, DMODEL);
  transpose_cast<float><<<dim3(DCC / 32, DMODEL / 32), tb, 0, stream>>>(Wkv_down, W1T + (long)DQC * DMODEL, DCC, DMODEL);
  transpose_cast<float><<<dim3(HQK / 32, DQC / 32), tb, 0, stream>>>(Wq_up, WquT, HQK, DQC);
  transpose_cast<float><<<dim3(HQK / 32, DCC / 32), tb, 0, stream>>>(Wk_up, WkvuT, HQK, DCC);
  transpose_cast<float><<<dim3(HV / 32, DCC / 32), tb, 0, stream>>>(Wv_up, WkvuT + (long)HQK * DCC, HV, DCC);
  transpose_cast<float><<<dim3(DMODEL / 32, HV / 32), tb, 0, stream>>>(Wo, WoT, DMODEL, HV);

  // fused down-projection: [qd | ckv] = hsb @ [Wq_down | Wkv_down]
  gemm_bt<<<dim3(NDOWN / 128, SEQ / 128), b256, 0, stream>>>(
      hsb, DMODEL, 0, W1T, DMODEL, 0, qdc, NDOWN, 0, DMODEL, 1.f, 0, 0);
  // q up-projection (scale folded in)
  gemm_bt<<<dim3(HQK / 128, SEQ / 128), b256, 0, stream>>>(
      qdc, NDOWN, 0, WquT, DQC, 0, qf, HQK, 0, DQC, scale, 0, 0);
  // fused k/v up-projection: [k | v] = ckv @ [Wk_up | Wv_up]
  gemm_bt<<<dim3(NKV / 128, SEQ / 128), b256, 0, stream>>>(
      qdc + DQC, NDOWN, 0, WkvuT, DCC, 0, kvf, NKV, 0, DCC, 1.f, 0, 0);

  rope_qk<<<dim3(SEQ * NHEADS * 32 / 256), b256, 0, stream>>>(qf, kvf);
  transpose_cast<bf16><<<dim3(HV / 32, SEQ / 32), tb, 0, stream>>>(kvf + HQK, vT, NKV, SEQ);

  // attention, nz heads per pass
  for (int h0 = 0; h0 < NHEADS; h0 += nz) {
    gemm_bt<<<dim3(SEQ / 128, SEQ / 128, nz), b256, 0, stream>>>(
        qf + h0 * DQKC, HQK, DQKC,
        kvf + h0 * DQKC, NKV, DQKC,
        SP, SEQ, (long)SEQ * SEQ, DQKC, 1.f, 0, /*causal=*/1);
    softmax_causal<<<dim3(SEQ, nz), b256, 0, stream>>>(SP);
    gemm_bt<<<dim3(DVC / 128, SEQ / 128, nz), b256, 0, stream>>>(
        SP, SEQ, (long)SEQ * SEQ,
        vT + (long)h0 * DVC * SEQ, SEQ, (long)DVC * SEQ,
        attn + h0 * DVC, HV, DVC, SEQ, 1.f, 0, /*causal=*/2);
  }

  // output projection (fp32 out)
  gemm_bt<<<dim3(DMODEL / 128, SEQ / 128), b256, 0, stream>>>(
      attn, HV, 0, WoT, HV, 0, d_out, DMODEL, 0, HV, 1.f, 1, 0);
}

// Round 3
// 426.074 us; speedup vs baseline: 1.2604x; 1.0626x over previous
//
#include <hip/hip_runtime.h>
#include <hip/hip_bf16.h>

using bf16 = __hip_bfloat16;
typedef __bf16 bf16x8v __attribute__((ext_vector_type(8)));
typedef float f32x4 __attribute__((ext_vector_type(4)));

static constexpr int SEQ = 2048;
static constexpr int DMODEL = 2048;
static constexpr int NHEADS = 16;
static constexpr int DQKC = 192;   // nope 128 + rope 64
static constexpr int DVC = 128;
static constexpr int DQC = 1536;
static constexpr int DCC = 512;
static constexpr int HQK = NHEADS * DQKC;  // 3072
static constexpr int HV = NHEADS * DVC;    // 2048
static constexpr int NKV = HQK + HV;       // 5120 (fused k_up|v_up output width)
static constexpr int NDOWN = DQC + DCC;    // 2048 (fused q_down|kv_down width)

typedef __attribute__((address_space(1))) const void* gas_ptr;
typedef __attribute__((address_space(3))) void* las_ptr;

__device__ __forceinline__ void g2l16(const void* g, void* l) {
  __builtin_amdgcn_global_load_lds((gas_ptr)g, (las_ptr)l, 16, 0, 0);
}

// C[M,N] = alpha * A[M,K] @ Bt[N,K]^T.  (causal paths unused since flash fusion)
__global__ __launch_bounds__(256) void gemm_bt(
    const bf16* __restrict__ A, int lda, long strideAz,
    const bf16* __restrict__ Bt, int ldb, long strideBz,
    void* __restrict__ Cv, int ldc, long strideCz,
    int K, float alpha, int c_fp32, int causal)
{
  if (causal == 1 && blockIdx.x > blockIdx.y) return;
  int Keff = K;
  if (causal == 2) Keff = min(K, ((int)blockIdx.y + 1) * 128);
  __shared__ __align__(16) bf16 As[128 * 32];
  __shared__ __align__(16) bf16 Bs[128 * 32];
  const int z = blockIdx.z;
  A += (long)z * strideAz;
  Bt += (long)z * strideBz;
  const int tid = threadIdx.x;
  const int wv = tid >> 6;
  const int lane = tid & 63;
  const int wm = (wv >> 1) * 64, wn = (wv & 1) * 64;
  const long tm = (long)blockIdx.y * 128, tn = (long)blockIdx.x * 128;
  const int r16 = lane >> 2;
  const int c8 = (lane & 3) * 8;
  const bf16* Ag = A + (tm + wv * 32 + r16) * lda + c8;
  const bf16* Bg = Bt + (tn + wv * 32 + r16) * ldb + c8;
  bf16* lA0 = &As[(wv * 32) * 32];
  bf16* lA1 = &As[(wv * 32 + 16) * 32];
  bf16* lB0 = &Bs[(wv * 32) * 32];
  bf16* lB1 = &Bs[(wv * 32 + 16) * 32];
  const int m0 = lane & 15;
  const int q8 = (lane >> 4) * 8;
  f32x4 acc[4][4] = {};
  for (int bk = 0; bk < Keff; bk += 32) {
    g2l16(Ag + bk, lA0);
    g2l16(Ag + bk + 16 * (long)lda, lA1);
    g2l16(Bg + bk, lB0);
    g2l16(Bg + bk + 16 * (long)ldb, lB1);
    __syncthreads();
    bf16x8v af[4], bfv[4];
#pragma unroll
    for (int i = 0; i < 4; i++)
      af[i] = *reinterpret_cast<const bf16x8v*>(&As[(wm + i * 16 + m0) * 32 + q8]);
#pragma unroll
    for (int i = 0; i < 4; i++)
      bfv[i] = *reinterpret_cast<const bf16x8v*>(&Bs[(wn + i * 16 + m0) * 32 + q8]);
#pragma unroll
    for (int mi = 0; mi < 4; mi++)
#pragma unroll
      for (int ni = 0; ni < 4; ni++)
        acc[mi][ni] = __builtin_amdgcn_mfma_f32_16x16x32_bf16(af[mi], bfv[ni], acc[mi][ni], 0, 0, 0);
    __syncthreads();
  }
  const int q4 = (lane >> 4) * 4;
  float* Cf = (float*)Cv;
  bf16* Cb = (bf16*)Cv;
  const long zc = (long)z * strideCz;
#pragma unroll
  for (int mi = 0; mi < 4; mi++) {
#pragma unroll
    for (int r = 0; r < 4; r++) {
      const long row = tm + wm + mi * 16 + q4 + r;
#pragma unroll
      for (int ni = 0; ni < 4; ni++) {
        const long idx = zc + row * ldc + tn + wn + ni * 16 + m0;
        const float v = acc[mi][ni][r] * alpha;
        if (c_fp32) Cf[idx] = v;
        else Cb[idx] = __float2bfloat16(v);
      }
    }
  }
}

// Fused flash attention: one block per (128-row Q-tile, head).
// 8 waves as 4 row-groups x 2 key-halves. K/V staged to LDS via
// global_load_lds; P (bf16) round-trips through LDS (C-layout -> A-layout).
// Online softmax: row max exchanged across the wave pair each iter; l kept
// as per-wave halves and combined once at the end.
__global__ __launch_bounds__(512) void flash_attn(
    const bf16* __restrict__ qf,   // [SEQ][HQK], 1/sqrt(dqk) pre-folded
    const bf16* __restrict__ kvf,  // [SEQ][NKV], k at col h*192
    const bf16* __restrict__ vT,   // [HV][SEQ]
    bf16* __restrict__ attn)       // [SEQ][HV]
{
  __shared__ __align__(16) bf16 Ks[6 * 128 * 32];  // [s][key][32 feat]
  __shared__ __align__(16) bf16 Vs[4 * 128 * 32];  // [ks][dv][32 keys]
  __shared__ __align__(16) bf16 Ps[128 * 132];     // [row][key], stride 132
  __shared__ float xbuf[8 * 32];
  const int h = blockIdx.y;
  const int tm = blockIdx.x * 128;
  const int tid = threadIdx.x;
  const int w = tid >> 6, lane = tid & 63;
  const int wr = w >> 1, wc = w & 1;
  const int m0 = lane & 15, quad = lane >> 4;
  const int q8 = quad * 8;

  bf16x8v qfr[2][6];
#pragma unroll
  for (int mi = 0; mi < 2; mi++)
#pragma unroll
    for (int s = 0; s < 6; s++)
      qfr[mi][s] = *reinterpret_cast<const bf16x8v*>(
          &qf[(long)(tm + wr * 32 + mi * 16 + m0) * HQK + h * DQKC + s * 32 + q8]);

  f32x4 O[2][8] = {};
  float mrow[2][4], lrow[2][4];
#pragma unroll
  for (int mi = 0; mi < 2; mi++)
#pragma unroll
    for (int r = 0; r < 4; r++) { mrow[mi][r] = -1e30f; lrow[mi][r] = 0.f; }

  for (int it = 0; it <= (int)blockIdx.x; ++it) {
    const int key0 = it * 128;
    // stage K-tile (48KB): chunk t -> LDS byte t*16; layouts chosen so frag
    // reads land on balanced banks without padding (row stride 32 hw).
#pragma unroll
    for (int i = 0; i < 6; i++) {
      const int t = i * 512 + tid;
      g2l16(kvf + (long)(key0 + ((t >> 2) & 127)) * NKV + h * DQKC + (t >> 9) * 32 + (t & 3) * 8,
            (char*)Ks + (t >> 6) * 1024);
    }
#pragma unroll
    for (int i = 0; i < 4; i++) {
      const int t = i * 512 + tid;
      g2l16(vT + (long)(h * DVC + ((t >> 2) & 127)) * SEQ + key0 + (t >> 9) * 32 + (t & 3) * 8,
            (char*)Vs + (t >> 6) * 1024);
    }
    __syncthreads();

    // S = Q @ K^T  (wave tile: 32 rows x 64 keys)
    f32x4 S[2][4] = {};
#pragma unroll
    for (int s = 0; s < 6; s++) {
      bf16x8v kb[4];
#pragma unroll
      for (int ni = 0; ni < 4; ni++)
        kb[ni] = *reinterpret_cast<const bf16x8v*>(
            &Ks[s * 4096 + (wc * 64 + ni * 16 + m0) * 32 + q8]);
#pragma unroll
      for (int mi = 0; mi < 2; mi++)
#pragma unroll
        for (int ni = 0; ni < 4; ni++)
          S[mi][ni] = __builtin_amdgcn_mfma_f32_16x16x32_bf16(qfr[mi][s], kb[ni], S[mi][ni], 0, 0, 0);
    }

    if (key0 == tm) {  // diagonal tile: causal mask
#pragma unroll
      for (int mi = 0; mi < 2; mi++)
#pragma unroll
        for (int ni = 0; ni < 4; ni++) {
          const int colo = wc * 64 + ni * 16 + m0;
          const int rowo = wr * 32 + mi * 16 + quad * 4;
#pragma unroll
          for (int r = 0; r < 4; r++)
            if (colo > rowo + r) S[mi][ni][r] = -1e30f;
        }
    }

    // wave-partial row max (this wave's 64 keys), then pair-exchange via LDS
    float pm[2][4];
#pragma unroll
    for (int mi = 0; mi < 2; mi++)
#pragma unroll
      for (int r = 0; r < 4; r++) {
        float v = fmaxf(fmaxf(S[mi][0][r], S[mi][1][r]), fmaxf(S[mi][2][r], S[mi][3][r]));
#pragma unroll
        for (int off = 1; off < 16; off <<= 1) v = fmaxf(v, __shfl_xor(v, off, 64));
        pm[mi][r] = v;
      }
    if (m0 == 0) {
#pragma unroll
      for (int mi = 0; mi < 2; mi++)
#pragma unroll
        for (int r = 0; r < 4; r++) xbuf[w * 32 + mi * 16 + quad * 4 + r] = pm[mi][r];
    }
    __syncthreads();
    float alph[2][4];
#pragma unroll
    for (int mi = 0; mi < 2; mi++)
#pragma unroll
      for (int r = 0; r < 4; r++) {
        const float mn = fmaxf(pm[mi][r], xbuf[(w ^ 1) * 32 + mi * 16 + quad * 4 + r]);
        alph[mi][r] = __expf(mrow[mi][r] - mn);
        mrow[mi][r] = mn;
      }

    // P = exp(S - m); write to LDS (bf16); per-wave partial row sums
    float ps[2][4] = {};
#pragma unroll
    for (int mi = 0; mi < 2; mi++)
#pragma unroll
      for (int ni = 0; ni < 4; ni++) {
        const int prow = wr * 32 + mi * 16 + quad * 4;
        const int pcol = wc * 64 + ni * 16 + m0;
#pragma unroll
        for (int r = 0; r < 4; r++) {
          const float p = __expf(S[mi][ni][r] - mrow[mi][r]);
          ps[mi][r] += p;
          Ps[(prow + r) * 132 + pcol] = __float2bfloat16(p);
        }
      }
#pragma unroll
    for (int mi = 0; mi < 2; mi++)
#pragma unroll
      for (int r = 0; r < 4; r++) {
        float v = ps[mi][r];
#pragma unroll
        for (int off = 1; off < 16; off <<= 1) v += __shfl_xor(v, off, 64);
        lrow[mi][r] = lrow[mi][r] * alph[mi][r] + v;
      }
    // rescale O
#pragma unroll
    for (int mi = 0; mi < 2; mi++)
#pragma unroll
      for (int ni = 0; ni < 8; ni++)
#pragma unroll
        for (int r = 0; r < 4; r++) O[mi][ni][r] *= alph[mi][r];
    __syncthreads();  // Ps visible to the wave pair

    // O += P @ V  (wave tile: 32 rows x 128 dv)
#pragma unroll
    for (int ks = 0; ks < 4; ks++) {
      bf16x8v pa[2], vb[8];
#pragma unroll
      for (int mi = 0; mi < 2; mi++)
        pa[mi] = *reinterpret_cast<const bf16x8v*>(
            &Ps[(wr * 32 + mi * 16 + m0) * 132 + ks * 32 + q8]);
#pragma unroll
      for (int ni = 0; ni < 8; ni++)
        vb[ni] = *reinterpret_cast<const bf16x8v*>(
            &Vs[ks * 4096 + (ni * 16 + m0) * 32 + q8]);
#pragma unroll
      for (int mi = 0; mi < 2; mi++)
#pragma unroll
        for (int ni = 0; ni < 8; ni++)
          O[mi][ni] = __builtin_amdgcn_mfma_f32_16x16x32_bf16(pa[mi], vb[ni], O[mi][ni], 0, 0, 0);
    }
    __syncthreads();  // PV reads done before next staging overwrites Ks/Vs
  }

  // combine l across the wave pair, normalize, store
  if (m0 == 0) {
#pragma unroll
    for (int mi = 0; mi < 2; mi++)
#pragma unroll
      for (int r = 0; r < 4; r++) xbuf[w * 32 + mi * 16 + quad * 4 + r] = lrow[mi][r];
  }
  __syncthreads();
#pragma unroll
  for (int mi = 0; mi < 2; mi++)
#pragma unroll
    for (int r = 0; r < 4; r++)
      lrow[mi][r] += xbuf[(w ^ 1) * 32 + mi * 16 + quad * 4 + r];
#pragma unroll
  for (int mi = 0; mi < 2; mi++) {
#pragma unroll
    for (int r = 0; r < 4; r++) {
      const long row = tm + wr * 32 + mi * 16 + quad * 4 + r;
      const float rl = 1.f / lrow[mi][r];
#pragma unroll
      for (int ni = 0; ni < 8; ni++)
        attn[row * HV + h * DVC + ni * 16 + m0] = __float2bfloat16(O[mi][ni][r] * rl);
    }
  }
}

__device__ __forceinline__ float tofl(float x) { return x; }
__device__ __forceinline__ float tofl(bf16 x) { return __bfloat162float(x); }

template <typename TIN>
__global__ __launch_bounds__(256) void transpose_cast(const TIN* __restrict__ in,
                                                      bf16* __restrict__ out,
                                                      int inStride, int outStride) {
  __shared__ float t[32][33];
  const int bx = blockIdx.x * 32, by = blockIdx.y * 32;
  const int tx = threadIdx.x, ty = threadIdx.y;
#pragma unroll
  for (int j = 0; j < 32; j += 8)
    t[ty + j][tx] = tofl(in[(long)(by + ty + j) * inStride + bx + tx]);
  __syncthreads();
#pragma unroll
  for (int j = 0; j < 32; j += 8)
    out[(long)(bx + ty + j) * outStride + by + tx] = __float2bfloat16(t[tx][ty + j]);
}

__global__ __launch_bounds__(256) void cast_f32_bf16(const float* __restrict__ in,
                                                     bf16* __restrict__ out, int n4) {
  int i = blockIdx.x * 256 + threadIdx.x;
  if (i < n4) {
    const float4 v = ((const float4*)in)[i];
    out[i * 4 + 0] = __float2bfloat16(v.x);
    out[i * 4 + 1] = __float2bfloat16(v.y);
    out[i * 4 + 2] = __float2bfloat16(v.z);
    out[i * 4 + 3] = __float2bfloat16(v.w);
  }
}

__global__ __launch_bounds__(256) void rope_qk(bf16* __restrict__ q, bf16* __restrict__ k) {
  const int idx = blockIdx.x * 256 + threadIdx.x;  // SEQ*NHEADS*32 threads
  const int i = idx & 31;
  const int h = (idx >> 5) & 15;
  const int l = idx >> 9;
  const float inv = powf(10000.f, -(float)i * (1.f / 32.f));
  float s, c;
  sincosf((float)l * inv, &s, &c);
  const long qb = (long)l * HQK + h * DQKC + 128;
  const long kb = (long)l * NKV + h * DQKC + 128;
  {
    float x0 = __bfloat162float(q[qb + i]);
    float x1 = __bfloat162float(q[qb + i + 32]);
    q[qb + i] = __float2bfloat16(x0 * c - x1 * s);
    q[qb + i + 32] = __float2bfloat16(x1 * c + x0 * s);
  }
  {
    float x0 = __bfloat162float(k[kb + i]);
    float x1 = __bfloat162float(k[kb + i + 32]);
    k[kb + i] = __float2bfloat16(x0 * c - x1 * s);
    k[kb + i + 32] = __float2bfloat16(x1 * c + x0 * s);
  }
}

extern "C" void kernel_launch(void* const* d_in, const int* in_sizes, int n_in,
                              void* d_out, int out_size, void* d_ws, size_t ws_size,
                              hipStream_t stream) {
  const float* hs      = (const float*)d_in[0];
  // d_in[1] attention_mask: exact causal mask; applied analytically.
  const float* Wq_down = (const float*)d_in[2];
  const float* Wq_up   = (const float*)d_in[3];
  const float* Wkv_down= (const float*)d_in[4];
  const float* Wk_up   = (const float*)d_in[5];
  const float* Wv_up   = (const float*)d_in[6];
  const float* Wo      = (const float*)d_in[7];

  char* p = (char*)d_ws;
  auto alloc = [&](long elems) {
    bf16* r = (bf16*)p;
    p += ((elems * 2 + 255) / 256) * 256;
    return r;
  };
  bf16* hsb   = alloc((long)SEQ * DMODEL);
  bf16* W1T   = alloc((long)NDOWN * DMODEL);
  bf16* WquT  = alloc((long)HQK * DQC);
  bf16* WkvuT = alloc((long)NKV * DCC);
  bf16* WoT   = alloc((long)DMODEL * HV);
  bf16* qdc   = alloc((long)SEQ * NDOWN);
  bf16* qf    = alloc((long)SEQ * HQK);
  bf16* kvf   = alloc((long)SEQ * NKV);
  bf16* vT    = alloc((long)HV * SEQ);
  bf16* attn  = alloc((long)SEQ * HV);

  const float scale = 0.07216878364870323f;  // 1/sqrt(192), folded into q

  const dim3 b256(256);
  const dim3 tb(32, 8);
  cast_f32_bf16<<<dim3(SEQ * DMODEL / 4 / 256), b256, 0, stream>>>(hs, hsb, SEQ * DMODEL / 4);
  transpose_cast<float><<<dim3(DQC / 32, DMODEL / 32), tb, 0, stream>>>(Wq_down, W1T, DQC, DMODEL);
  transpose_cast<float><<<dim3(DCC / 32, DMODEL / 32), tb, 0, stream>>>(Wkv_down, W1T + (long)DQC * DMODEL, DCC, DMODEL);
  transpose_cast<float><<<dim3(HQK / 32, DQC / 32), tb, 0, stream>>>(Wq_up, WquT, HQK, DQC);
  transpose_cast<float><<<dim3(HQK / 32, DCC / 32), tb, 0, stream>>>(Wk_up, WkvuT, HQK, DCC);
  transpose_cast<float><<<dim3(HV / 32, DCC / 32), tb, 0, stream>>>(Wv_up, WkvuT + (long)HQK * DCC, HV, DCC);
  transpose_cast<float><<<dim3(DMODEL / 32, HV / 32), tb, 0, stream>>>(Wo, WoT, DMODEL, HV);

  // fused down-projection: [qd | ckv] = hsb @ [Wq_down | Wkv_down]
  gemm_bt<<<dim3(NDOWN / 128, SEQ / 128), b256, 0, stream>>>(
      hsb, DMODEL, 0, W1T, DMODEL, 0, qdc, NDOWN, 0, DMODEL, 1.f, 0, 0);
  // q up-projection (scale folded in)
  gemm_bt<<<dim3(HQK / 128, SEQ / 128), b256, 0, stream>>>(
      qdc, NDOWN, 0, WquT, DQC, 0, qf, HQK, 0, DQC, scale, 0, 0);
  // fused k/v up-projection: [k | v] = ckv @ [Wk_up | Wv_up]
  gemm_bt<<<dim3(NKV / 128, SEQ / 128), b256, 0, stream>>>(
      qdc + DQC, NDOWN, 0, WkvuT, DCC, 0, kvf, NKV, 0, DCC, 1.f, 0, 0);

  rope_qk<<<dim3(SEQ * NHEADS * 32 / 256), b256, 0, stream>>>(qf, kvf);
  transpose_cast<bf16><<<dim3(HV / 32, SEQ / 32), tb, 0, stream>>>(kvf + HQK, vT, NKV, SEQ);

  // fused attention (QK^T + online softmax + PV)
  flash_attn<<<dim3(SEQ / 128, NHEADS), dim3(512), 0, stream>>>(qf, kvf, vT, attn);

  // output projection (fp32 out)
  gemm_bt<<<dim3(DMODEL / 128, SEQ / 128), b256, 0, stream>>>(
      attn, HV, 0, WoT, HV, 0, d_out, DMODEL, 0, HV, 1.f, 1, 0);
}

// Round 4
// 383.208 us; speedup vs baseline: 1.4014x; 1.1119x over previous
//
#include <hip/hip_runtime.h>
#include <hip/hip_bf16.h>

using bf16 = __hip_bfloat16;
typedef __bf16 bf16x8v __attribute__((ext_vector_type(8)));
typedef float f32x4 __attribute__((ext_vector_type(4)));

static constexpr int SEQ = 2048;
static constexpr int DMODEL = 2048;
static constexpr int NHEADS = 16;
static constexpr int DQKC = 192;   // nope 128 + rope 64
static constexpr int DVC = 128;
static constexpr int DQC = 1536;
static constexpr int DCC = 512;
static constexpr int HQK = NHEADS * DQKC;  // 3072
static constexpr int HV = NHEADS * DVC;    // 2048
static constexpr int NKV = HQK + HV;       // 5120 (fused k_up|v_up output width)
static constexpr int NDOWN = DQC + DCC;    // 2048 (fused q_down|kv_down width)

typedef __attribute__((address_space(1))) const void* gas_ptr;
typedef __attribute__((address_space(3))) void* las_ptr;

__device__ __forceinline__ void g2l16(const void* g, void* l) {
  __builtin_amdgcn_global_load_lds((gas_ptr)g, (las_ptr)l, 16, 0, 0);
}

// C[M,N] = alpha * A[M,K] @ Bt[N,K]^T.
__global__ __launch_bounds__(256) void gemm_bt(
    const bf16* __restrict__ A, int lda, long strideAz,
    const bf16* __restrict__ Bt, int ldb, long strideBz,
    void* __restrict__ Cv, int ldc, long strideCz,
    int K, float alpha, int c_fp32, int causal)
{
  if (causal == 1 && blockIdx.x > blockIdx.y) return;
  int Keff = K;
  if (causal == 2) Keff = min(K, ((int)blockIdx.y + 1) * 128);
  __shared__ __align__(16) bf16 As[128 * 32];
  __shared__ __align__(16) bf16 Bs[128 * 32];
  const int z = blockIdx.z;
  A += (long)z * strideAz;
  Bt += (long)z * strideBz;
  const int tid = threadIdx.x;
  const int wv = tid >> 6;
  const int lane = tid & 63;
  const int wm = (wv >> 1) * 64, wn = (wv & 1) * 64;
  const long tm = (long)blockIdx.y * 128, tn = (long)blockIdx.x * 128;
  const int r16 = lane >> 2;
  const int c8 = (lane & 3) * 8;
  const bf16* Ag = A + (tm + wv * 32 + r16) * lda + c8;
  const bf16* Bg = Bt + (tn + wv * 32 + r16) * ldb + c8;
  bf16* lA0 = &As[(wv * 32) * 32];
  bf16* lA1 = &As[(wv * 32 + 16) * 32];
  bf16* lB0 = &Bs[(wv * 32) * 32];
  bf16* lB1 = &Bs[(wv * 32 + 16) * 32];
  const int m0 = lane & 15;
  const int q8 = (lane >> 4) * 8;
  f32x4 acc[4][4] = {};
  for (int bk = 0; bk < Keff; bk += 32) {
    g2l16(Ag + bk, lA0);
    g2l16(Ag + bk + 16 * (long)lda, lA1);
    g2l16(Bg + bk, lB0);
    g2l16(Bg + bk + 16 * (long)ldb, lB1);
    __syncthreads();
    bf16x8v af[4], bfv[4];
#pragma unroll
    for (int i = 0; i < 4; i++)
      af[i] = *reinterpret_cast<const bf16x8v*>(&As[(wm + i * 16 + m0) * 32 + q8]);
#pragma unroll
    for (int i = 0; i < 4; i++)
      bfv[i] = *reinterpret_cast<const bf16x8v*>(&Bs[(wn + i * 16 + m0) * 32 + q8]);
#pragma unroll
    for (int mi = 0; mi < 4; mi++)
#pragma unroll
      for (int ni = 0; ni < 4; ni++)
        acc[mi][ni] = __builtin_amdgcn_mfma_f32_16x16x32_bf16(af[mi], bfv[ni], acc[mi][ni], 0, 0, 0);
    __syncthreads();
  }
  const int q4 = (lane >> 4) * 4;
  float* Cf = (float*)Cv;
  bf16* Cb = (bf16*)Cv;
  const long zc = (long)z * strideCz;
#pragma unroll
  for (int mi = 0; mi < 4; mi++) {
#pragma unroll
    for (int r = 0; r < 4; r++) {
      const long row = tm + wm + mi * 16 + q4 + r;
#pragma unroll
      for (int ni = 0; ni < 4; ni++) {
        const long idx = zc + row * ldc + tn + wn + ni * 16 + m0;
        const float v = acc[mi][ni][r] * alpha;
        if (c_fp32) Cf[idx] = v;
        else Cb[idx] = __float2bfloat16(v);
      }
    }
  }
}

// Fused flash attention v2.
// 512 blocks x 256 threads; block = (64-row Q-tile, head) via a pairing
// swizzle: flat id and id+256 map to complementary tiles (t, 31-t) so each
// CU's two co-resident blocks total exactly 17 key-tile iterations.
// Each wave owns 16 Q-rows end-to-end: computes S^T = K @ Q^T (operand swap
// puts P's row index on lane&15), wave-local online softmax (m,l,alpha are
// per-lane scalars), P round-trip through wave-private LDS, PV non-redundant.
// LDS: Ks 48K + Vs 32K = 80K exactly -> 2 blocks/CU. Ps (16K) aliases Ks.
// All LDS layouts XOR-swizzled at 16B granularity (g2l16 allows per-lane
// GLOBAL source; dest stays wave-uniform+lane*16) -> frag reads 2-way = free.
__global__ __launch_bounds__(256) void flash_attn(
    const bf16* __restrict__ qf,   // [SEQ][HQK], 1/sqrt(dqk) pre-folded
    const bf16* __restrict__ kvf,  // [SEQ][NKV], k at col h*192
    const bf16* __restrict__ vT,   // [HV][SEQ]
    bf16* __restrict__ attn)       // [SEQ][HV]
{
  // Ks: unit(key,fg) = key*24 + (fg ^ (key&7)),  fg = feat/8 (0..23)   [48K]
  // Vs: unit(dv,kg)  = dv*16 + (kg ^ (dv&15)),   kg = key/8 (0..15)    [32K] at +49152
  // Ps: unit(row,k8) = row*16 + (k8 ^ (row&15)), k8 = key/8 (0..15)    [16K] aliases Ks
  __shared__ __align__(16) char smem[81920];
  const int fid = blockIdx.x;
  const int half = fid >> 8;
  const int r8 = fid & 255;
  const int h = r8 & 15;
  const int t8 = r8 >> 4;
  const int tile = half ? (31 - t8) : t8;
  const int nkt = (tile >> 1) + 1;           // 128-key tiles needed
  const int tid = threadIdx.x;
  const int w = tid >> 6, lane = tid & 63;
  const int m0 = lane & 15, quad = lane >> 4;
  const int prow = w * 16 + m0;              // this lane's P/Q row (block-local)
  const long qrow = (long)tile * 64 + prow;  // global Q row

  bf16x8v qfr[6];
#pragma unroll
  for (int s = 0; s < 6; s++)
    qfr[s] = *reinterpret_cast<const bf16x8v*>(
        &qf[qrow * HQK + h * DQKC + s * 32 + quad * 8]);

  f32x4 O[8] = {};
  float mrow = -1e30f, lrow = 0.f;

  for (int kt = 0; kt < nkt; ++kt) {
    const int key0 = kt * 128;
    // ---- stage K (3072 units) and V (2048 units) ----
#pragma unroll
    for (int i = 0; i < 12; i++) {
      const int u = i * 256 + tid;
      const int key = u / 24;
      const int fg = (u - key * 24) ^ (key & 7);
      g2l16(kvf + (long)(key0 + key) * NKV + h * DQKC + fg * 8, smem + u * 16);
    }
#pragma unroll
    for (int i = 0; i < 8; i++) {
      const int u = i * 256 + tid;
      const int dv = u >> 4;
      const int kg = (u & 15) ^ (dv & 15);
      g2l16(vT + (long)(h * DVC + dv) * SEQ + key0 + kg * 8, smem + 49152 + u * 16);
    }
    __syncthreads();

    // ---- S^T = K @ Q^T : C row = key (quad*4+r), col = qrow (lane&15) ----
    f32x4 S[8] = {};
#pragma unroll
    for (int s = 0; s < 6; s++) {
#pragma unroll
      for (int mi = 0; mi < 8; mi++) {
        const int kl = mi * 16 + m0;
        const int idx = kl * 24 + ((s * 4 + quad) ^ (m0 & 7));
        const bf16x8v kb = *reinterpret_cast<const bf16x8v*>(smem + idx * 16);
        S[mi] = __builtin_amdgcn_mfma_f32_16x16x32_bf16(kb, qfr[s], S[mi], 0, 0, 0);
      }
    }
    if (kt == nkt - 1) {  // causal mask on the diagonal tile
#pragma unroll
      for (int mi = 0; mi < 8; mi++)
#pragma unroll
        for (int r = 0; r < 4; r++)
          if (key0 + mi * 16 + quad * 4 + r > qrow) S[mi][r] = -1e30f;
    }

    // ---- wave-local online softmax (per-lane scalars, row = m0) ----
    float fm = -1e30f;
#pragma unroll
    for (int mi = 0; mi < 8; mi++)
#pragma unroll
      for (int r = 0; r < 4; r++) fm = fmaxf(fm, S[mi][r]);
    fm = fmaxf(fm, __shfl_xor(fm, 16, 64));
    fm = fmaxf(fm, __shfl_xor(fm, 32, 64));
    const float newm = fmaxf(mrow, fm);
    const float alph = __expf(mrow - newm);
    mrow = newm;
    float ps = 0.f;
#pragma unroll
    for (int mi = 0; mi < 8; mi++)
#pragma unroll
      for (int r = 0; r < 4; r++) {
        const float p = __expf(S[mi][r] - newm);
        S[mi][r] = p;
        ps += p;
      }
    ps += __shfl_xor(ps, 16, 64);
    ps += __shfl_xor(ps, 32, 64);
    lrow = lrow * alph + ps;

    __syncthreads();  // all QK reads of Ks done before Ps (alias) is written

    // ---- P -> LDS (b64, wave-private rows) + O rescale ----
#pragma unroll
    for (int mi = 0; mi < 8; mi++) {
      const int k8 = mi * 2 + (quad >> 1);
      const int idx = prow * 16 + (k8 ^ (m0 & 15));
      union { unsigned int u[2]; } pk;
      unsigned short b[4];
#pragma unroll
      for (int r = 0; r < 4; r++) {
        const bf16 t = __float2bfloat16(S[mi][r]);
        b[r] = *reinterpret_cast<const unsigned short*>(&t);
      }
      pk.u[0] = (unsigned)b[0] | ((unsigned)b[1] << 16);
      pk.u[1] = (unsigned)b[2] | ((unsigned)b[3] << 16);
      *reinterpret_cast<uint2*>(smem + idx * 16 + (quad & 1) * 8) =
          make_uint2(pk.u[0], pk.u[1]);
    }
    float aO[4];
#pragma unroll
    for (int r = 0; r < 4; r++) aO[r] = __shfl(alph, quad * 4 + r, 16);
#pragma unroll
    for (int ni = 0; ni < 8; ni++)
#pragma unroll
      for (int r = 0; r < 4; r++) O[ni][r] *= aO[r];
    // NOTE: no barrier needed here — PV reads only this wave's own Ps rows
    // (same-wave LDS ordering) and Vs staged before sync above.

    // ---- O += P @ V ----
#pragma unroll
    for (int ks = 0; ks < 4; ks++) {
      const int idxp = prow * 16 + ((ks * 4 + quad) ^ (m0 & 15));
      const bf16x8v pa = *reinterpret_cast<const bf16x8v*>(smem + idxp * 16);
#pragma unroll
      for (int ni = 0; ni < 8; ni++) {
        const int dv = ni * 16 + m0;
        const int idxv = dv * 16 + ((ks * 4 + quad) ^ (dv & 15));
        const bf16x8v vb = *reinterpret_cast<const bf16x8v*>(smem + 49152 + idxv * 16);
        O[ni] = __builtin_amdgcn_mfma_f32_16x16x32_bf16(pa, vb, O[ni], 0, 0, 0);
      }
    }
    __syncthreads();  // PV reads (Ps+Vs) done before next iter's staging
  }

  // ---- normalize and store: O row = quad*4+r, col dv = ni*16+m0 ----
  float lO[4];
#pragma unroll
  for (int r = 0; r < 4; r++) lO[r] = 1.f / __shfl(lrow, quad * 4 + r, 16);
#pragma unroll
  for (int ni = 0; ni < 8; ni++)
#pragma unroll
    for (int r = 0; r < 4; r++)
      attn[((long)tile * 64 + w * 16 + quad * 4 + r) * HV + h * DVC + ni * 16 + m0] =
          __float2bfloat16(O[ni][r] * lO[r]);
}

__device__ __forceinline__ float tofl(float x) { return x; }
__device__ __forceinline__ float tofl(bf16 x) { return __bfloat162float(x); }

template <typename TIN>
__global__ __launch_bounds__(256) void transpose_cast(const TIN* __restrict__ in,
                                                      bf16* __restrict__ out,
                                                      int inStride, int outStride) {
  __shared__ float t[32][33];
  const int bx = blockIdx.x * 32, by = blockIdx.y * 32;
  const int tx = threadIdx.x, ty = threadIdx.y;
#pragma unroll
  for (int j = 0; j < 32; j += 8)
    t[ty + j][tx] = tofl(in[(long)(by + ty + j) * inStride + bx + tx]);
  __syncthreads();
#pragma unroll
  for (int j = 0; j < 32; j += 8)
    out[(long)(bx + ty + j) * outStride + by + tx] = __float2bfloat16(t[tx][ty + j]);
}

__global__ __launch_bounds__(256) void cast_f32_bf16(const float* __restrict__ in,
                                                     bf16* __restrict__ out, int n4) {
  int i = blockIdx.x * 256 + threadIdx.x;
  if (i < n4) {
    const float4 v = ((const float4*)in)[i];
    out[i * 4 + 0] = __float2bfloat16(v.x);
    out[i * 4 + 1] = __float2bfloat16(v.y);
    out[i * 4 + 2] = __float2bfloat16(v.z);
    out[i * 4 + 3] = __float2bfloat16(v.w);
  }
}

__global__ __launch_bounds__(256) void rope_qk(bf16* __restrict__ q, bf16* __restrict__ k) {
  const int idx = blockIdx.x * 256 + threadIdx.x;  // SEQ*NHEADS*32 threads
  const int i = idx & 31;
  const int h = (idx >> 5) & 15;
  const int l = idx >> 9;
  const float inv = powf(10000.f, -(float)i * (1.f / 32.f));
  float s, c;
  sincosf((float)l * inv, &s, &c);
  const long qb = (long)l * HQK + h * DQKC + 128;
  const long kb = (long)l * NKV + h * DQKC + 128;
  {
    float x0 = __bfloat162float(q[qb + i]);
    float x1 = __bfloat162float(q[qb + i + 32]);
    q[qb + i] = __float2bfloat16(x0 * c - x1 * s);
    q[qb + i + 32] = __float2bfloat16(x1 * c + x0 * s);
  }
  {
    float x0 = __bfloat162float(k[kb + i]);
    float x1 = __bfloat162float(k[kb + i + 32]);
    k[kb + i] = __float2bfloat16(x0 * c - x1 * s);
    k[kb + i + 32] = __float2bfloat16(x1 * c + x0 * s);
  }
}

extern "C" void kernel_launch(void* const* d_in, const int* in_sizes, int n_in,
                              void* d_out, int out_size, void* d_ws, size_t ws_size,
                              hipStream_t stream) {
  const float* hs      = (const float*)d_in[0];
  // d_in[1] attention_mask: exact causal mask; applied analytically.
  const float* Wq_down = (const float*)d_in[2];
  const float* Wq_up   = (const float*)d_in[3];
  const float* Wkv_down= (const float*)d_in[4];
  const float* Wk_up   = (const float*)d_in[5];
  const float* Wv_up   = (const float*)d_in[6];
  const float* Wo      = (const float*)d_in[7];

  char* p = (char*)d_ws;
  auto alloc = [&](long elems) {
    bf16* r = (bf16*)p;
    p += ((elems * 2 + 255) / 256) * 256;
    return r;
  };
  bf16* hsb   = alloc((long)SEQ * DMODEL);
  bf16* W1T   = alloc((long)NDOWN * DMODEL);
  bf16* WquT  = alloc((long)HQK * DQC);
  bf16* WkvuT = alloc((long)NKV * DCC);
  bf16* WoT   = alloc((long)DMODEL * HV);
  bf16* qdc   = alloc((long)SEQ * NDOWN);
  bf16* qf    = alloc((long)SEQ * HQK);
  bf16* kvf   = alloc((long)SEQ * NKV);
  bf16* vT    = alloc((long)HV * SEQ);
  bf16* attn  = alloc((long)SEQ * HV);

  const float scale = 0.07216878364870323f;  // 1/sqrt(192), folded into q

  const dim3 b256(256);
  const dim3 tb(32, 8);
  cast_f32_bf16<<<dim3(SEQ * DMODEL / 4 / 256), b256, 0, stream>>>(hs, hsb, SEQ * DMODEL / 4);
  transpose_cast<float><<<dim3(DQC / 32, DMODEL / 32), tb, 0, stream>>>(Wq_down, W1T, DQC, DMODEL);
  transpose_cast<float><<<dim3(DCC / 32, DMODEL / 32), tb, 0, stream>>>(Wkv_down, W1T + (long)DQC * DMODEL, DCC, DMODEL);
  transpose_cast<float><<<dim3(HQK / 32, DQC / 32), tb, 0, stream>>>(Wq_up, WquT, HQK, DQC);
  transpose_cast<float><<<dim3(HQK / 32, DCC / 32), tb, 0, stream>>>(Wk_up, WkvuT, HQK, DCC);
  transpose_cast<float><<<dim3(HV / 32, DCC / 32), tb, 0, stream>>>(Wv_up, WkvuT + (long)HQK * DCC, HV, DCC);
  transpose_cast<float><<<dim3(DMODEL / 32, HV / 32), tb, 0, stream>>>(Wo, WoT, DMODEL, HV);

  // fused down-projection: [qd | ckv] = hsb @ [Wq_down | Wkv_down]
  gemm_bt<<<dim3(NDOWN / 128, SEQ / 128), b256, 0, stream>>>(
      hsb, DMODEL, 0, W1T, DMODEL, 0, qdc, NDOWN, 0, DMODEL, 1.f, 0, 0);
  // q up-projection (scale folded in)
  gemm_bt<<<dim3(HQK / 128, SEQ / 128), b256, 0, stream>>>(
      qdc, NDOWN, 0, WquT, DQC, 0, qf, HQK, 0, DQC, scale, 0, 0);
  // fused k/v up-projection: [k | v] = ckv @ [Wk_up | Wv_up]
  gemm_bt<<<dim3(NKV / 128, SEQ / 128), b256, 0, stream>>>(
      qdc + DQC, NDOWN, 0, WkvuT, DCC, 0, kvf, NKV, 0, DCC, 1.f, 0, 0);

  rope_qk<<<dim3(SEQ * NHEADS * 32 / 256), b256, 0, stream>>>(qf, kvf);
  transpose_cast<bf16><<<dim3(HV / 32, SEQ / 32), tb, 0, stream>>>(kvf + HQK, vT, NKV, SEQ);

  // fused attention (QK^T + online softmax + PV), balanced 64-row tiles
  flash_attn<<<dim3(512), b256, 0, stream>>>(qf, kvf, vT, attn);

  // output projection (fp32 out)
  gemm_bt<<<dim3(DMODEL / 128, SEQ / 128), b256, 0, stream>>>(
      attn, HV, 0, WoT, HV, 0, d_out, DMODEL, 0, HV, 1.f, 1, 0);
}

// Round 7
// 341.143 us; speedup vs baseline: 1.5742x; 1.1233x over previous
//
#include <hip/hip_runtime.h>
#include <hip/hip_bf16.h>

using bf16 = __hip_bfloat16;
typedef __bf16 bf16x8v __attribute__((ext_vector_type(8)));
typedef float f32x4 __attribute__((ext_vector_type(4)));

static constexpr int SEQ = 2048;
static constexpr int DMODEL = 2048;
static constexpr int NHEADS = 16;
static constexpr int DQKC = 192;   // nope 128 + rope 64
static constexpr int DVC = 128;
static constexpr int DQC = 1536;
static constexpr int DCC = 512;
static constexpr int HQK = NHEADS * DQKC;  // 3072
static constexpr int HV = NHEADS * DVC;    // 2048
static constexpr int NKV = HQK + HV;       // 5120
static constexpr int NDOWN = DQC + DCC;    // 2048

typedef __attribute__((address_space(1))) const void* gas_ptr;
typedef __attribute__((address_space(3))) void* las_ptr;

__device__ __forceinline__ void g2l16(const void* g, void* l) {
  __builtin_amdgcn_global_load_lds((gas_ptr)g, (las_ptr)l, 16, 0, 0);
}

// ---------------- templated GEMM core: C[M,N] = alpha * A@Bt^T ----------------
// BM x BN block tile, 4 waves as 2x2 of (BM/2)x(BN/2), BK=32.
template <int BM, int BN>
__device__ __forceinline__ void gemm_core(
    const bf16* __restrict__ A, int lda,
    const bf16* __restrict__ Bt, int ldb,
    void* __restrict__ Cv, int ldc,
    int K, float alpha, int c_fp32, long tm, long tn, char* smem)
{
  constexpr int FM = BM / 32, FN = BN / 32;
  bf16* As = (bf16*)smem;              // [BM][32]
  char* Bsm = smem + BM * 64;          // [BN][32]
  bf16* Bs = (bf16*)Bsm;
  const int tid = threadIdx.x;
  const int w = tid >> 6, lane = tid & 63;
  const int wm = (w >> 1) * (BM / 2), wn = (w & 1) * (BN / 2);
  const int m0 = lane & 15, q8 = (lane >> 4) * 8;
  f32x4 acc[FM][FN] = {};
  for (int bk = 0; bk < K; bk += 32) {
#pragma unroll
    for (int i = 0; i < BM / 64; i++) {
      const int u = i * 256 + tid;
      g2l16(A + (tm + (u >> 2)) * (long)lda + bk + (u & 3) * 8, smem + u * 16);
    }
#pragma unroll
    for (int i = 0; i < BN / 64; i++) {
      const int u = i * 256 + tid;
      g2l16(Bt + (tn + (u >> 2)) * (long)ldb + bk + (u & 3) * 8, Bsm + u * 16);
    }
    __syncthreads();
    bf16x8v af[FM], bfv[FN];
#pragma unroll
    for (int i = 0; i < FM; i++)
      af[i] = *reinterpret_cast<const bf16x8v*>(&As[(wm + i * 16 + m0) * 32 + q8]);
#pragma unroll
    for (int i = 0; i < FN; i++)
      bfv[i] = *reinterpret_cast<const bf16x8v*>(&Bs[(wn + i * 16 + m0) * 32 + q8]);
#pragma unroll
    for (int mi = 0; mi < FM; mi++)
#pragma unroll
      for (int ni = 0; ni < FN; ni++)
        acc[mi][ni] = __builtin_amdgcn_mfma_f32_16x16x32_bf16(af[mi], bfv[ni], acc[mi][ni], 0, 0, 0);
    __syncthreads();
  }
  const int q4 = (lane >> 4) * 4;
  float* Cf = (float*)Cv;
  bf16* Cb = (bf16*)Cv;
#pragma unroll
  for (int mi = 0; mi < FM; mi++) {
#pragma unroll
    for (int r = 0; r < 4; r++) {
      const long row = tm + wm + mi * 16 + q4 + r;
#pragma unroll
      for (int ni = 0; ni < FN; ni++) {
        const long idx = row * ldc + tn + wn + ni * 16 + m0;
        const float v = acc[mi][ni][r] * alpha;
        if (c_fp32) Cf[idx] = v;
        else Cb[idx] = __float2bfloat16(v);
      }
    }
  }
}

__global__ __launch_bounds__(256) void gemm64(
    const bf16* __restrict__ A, int lda, const bf16* __restrict__ Bt, int ldb,
    void* __restrict__ Cv, int ldc, int K, float alpha, int c_fp32)
{
  __shared__ __align__(16) char smem[(64 + 128) * 64];
  gemm_core<64, 128>(A, lda, Bt, ldb, Cv, ldc, K, alpha, c_fp32,
                     (long)blockIdx.y * 64, (long)blockIdx.x * 128, smem);
}

// two independent GEMMs in one launch (grid.x split at nx1)
__global__ __launch_bounds__(256) void gemm_dual(
    const bf16* __restrict__ A1, int lda1, const bf16* __restrict__ B1, int ldb1,
    void* __restrict__ C1, int ldc1, int K1, float alpha1, int nx1,
    const bf16* __restrict__ A2, int lda2, const bf16* __restrict__ B2, int ldb2,
    void* __restrict__ C2, int ldc2, int K2)
{
  __shared__ __align__(16) char smem[(64 + 128) * 64];
  if ((int)blockIdx.x < nx1)
    gemm_core<64, 128>(A1, lda1, B1, ldb1, C1, ldc1, K1, alpha1, 0,
                       (long)blockIdx.y * 64, (long)blockIdx.x * 128, smem);
  else
    gemm_core<64, 128>(A2, lda2, B2, ldb2, C2, ldc2, K2, 1.f, 0,
                       (long)blockIdx.y * 64, (long)((int)blockIdx.x - nx1) * 128, smem);
}

// ---------------- fused flash attention v3.1 (96-key tiles, 68KB LDS) --------
// 512 blocks x 256 thr; block = (64-row q-tile, head), pairing swizzle.
// Ks: 96 keys x 24 fg : unit = key*24 + (fg ^ (key&7))          [36864 B]
// Vs: 128 dv x 16 kg  : unit = dv*16 + (kg ^ (dv&15))           [32768 B] at +36864
//     NOTE: all 16 kg staged UNGUARDED — a divergent guard on g2l16 shifts the
//     wave-uniform LDS base (readfirstlane of first ACTIVE lane) and corrupts
//     the write (round-5 bug). Logical kg 12..15 are written but never read.
// Ps: 64 rows x 16 k8 : unit = row*16 + (k8 ^ (row&15))         [16384 B] aliases Ks
__global__ __launch_bounds__(256) void flash_attn(
    const bf16* __restrict__ qf,   // [SEQ][HQK], 1/sqrt(dqk) pre-folded
    const bf16* __restrict__ kvf,  // [SEQ][NKV], k at col h*192
    const bf16* __restrict__ vT,   // [HV][SEQ]
    bf16* __restrict__ attn)       // [SEQ][HV]
{
  __shared__ __align__(16) char smem[69632];
  const int fid = blockIdx.x;
  const int half = fid >> 8;
  const int r8 = fid & 255;
  const int h = r8 & 15;
  const int t8 = r8 >> 4;
  const int tile = half ? (31 - t8) : t8;
  const int nkt = (tile * 64 + 63) / 96 + 1;  // 96-key tiles to cover diagonal
  const int tid = threadIdx.x;
  const int w = tid >> 6, lane = tid & 63;
  const int m0 = lane & 15, quad = lane >> 4;
  const int prow = w * 16 + m0;
  const long qrow = (long)tile * 64 + prow;

  bf16x8v qfr[6];
#pragma unroll
  for (int s = 0; s < 6; s++)
    qfr[s] = *reinterpret_cast<const bf16x8v*>(
        &qf[qrow * HQK + h * DQKC + s * 32 + quad * 8]);

  f32x4 O[8] = {};
  float mrow = -1e30f, lrow = 0.f;

  for (int kt = 0; kt < nkt; ++kt) {
    const int key0 = kt * 96;
    // stage K: 2304 units (9 rounds)
#pragma unroll
    for (int i = 0; i < 9; i++) {
      const int u = i * 256 + tid;
      const int key = u / 24;
      const int fg = (u - key * 24) ^ (key & 7);
      g2l16(kvf + (long)(key0 + key) * NKV + h * DQKC + fg * 8, smem + u * 16);
    }
    // stage V: all 2048 units, no guard (see header comment)
#pragma unroll
    for (int i = 0; i < 8; i++) {
      const int u = i * 256 + tid;
      const int dv = u >> 4;
      const int kg = (u & 15) ^ (dv & 15);
      g2l16(vT + (long)(h * DVC + dv) * SEQ + key0 + kg * 8, smem + 36864 + u * 16);
    }
    __syncthreads();

    // S^T = K @ Q^T : C row = key (quad*4+r), col = qrow (m0)
    f32x4 S[6] = {};
#pragma unroll
    for (int s = 0; s < 6; s++) {
#pragma unroll
      for (int mi = 0; mi < 6; mi++) {
        const int kl = mi * 16 + m0;
        const int idx = kl * 24 + ((s * 4 + quad) ^ (m0 & 7));
        const bf16x8v kb = *reinterpret_cast<const bf16x8v*>(smem + idx * 16);
        S[mi] = __builtin_amdgcn_mfma_f32_16x16x32_bf16(kb, qfr[s], S[mi], 0, 0, 0);
      }
    }
    if (key0 + 95 > tile * 64) {  // tile touches/passes the diagonal
#pragma unroll
      for (int mi = 0; mi < 6; mi++)
#pragma unroll
        for (int r = 0; r < 4; r++)
          if (key0 + mi * 16 + quad * 4 + r > qrow) S[mi][r] = -1e30f;
    }

    // wave-local online softmax (row = m0; partners at lane^16, lane^32)
    float fm = -1e30f;
#pragma unroll
    for (int mi = 0; mi < 6; mi++)
#pragma unroll
      for (int r = 0; r < 4; r++) fm = fmaxf(fm, S[mi][r]);
    fm = fmaxf(fm, __shfl_xor(fm, 16, 64));
    fm = fmaxf(fm, __shfl_xor(fm, 32, 64));
    const float newm = fmaxf(mrow, fm);
    const float alph = __expf(mrow - newm);
    mrow = newm;
    float ps = 0.f;
#pragma unroll
    for (int mi = 0; mi < 6; mi++)
#pragma unroll
      for (int r = 0; r < 4; r++) {
        const float p = __expf(S[mi][r] - newm);
        S[mi][r] = p;
        ps += p;
      }
    ps += __shfl_xor(ps, 16, 64);
    ps += __shfl_xor(ps, 32, 64);
    lrow = lrow * alph + ps;

    __syncthreads();  // all QK reads of Ks done before Ps (alias) is written

    // P -> LDS (b64, wave-private rows)
#pragma unroll
    for (int mi = 0; mi < 6; mi++) {
      const int k8 = mi * 2 + (quad >> 1);
      const int idx = prow * 16 + (k8 ^ (m0 & 15));
      unsigned short b[4];
#pragma unroll
      for (int r = 0; r < 4; r++) {
        const bf16 t = __float2bfloat16(S[mi][r]);
        b[r] = *reinterpret_cast<const unsigned short*>(&t);
      }
      *reinterpret_cast<uint2*>(smem + idx * 16 + (quad & 1) * 8) =
          make_uint2((unsigned)b[0] | ((unsigned)b[1] << 16),
                     (unsigned)b[2] | ((unsigned)b[3] << 16));
    }
    float aO[4];
#pragma unroll
    for (int r = 0; r < 4; r++) aO[r] = __shfl(alph, quad * 4 + r, 16);
#pragma unroll
    for (int ni = 0; ni < 8; ni++)
#pragma unroll
      for (int r = 0; r < 4; r++) O[ni][r] *= aO[r];
    // no barrier: PV reads only this wave's own Ps rows + Vs (staged pre-sync)

    // O += P @ V
#pragma unroll
    for (int ks = 0; ks < 3; ks++) {
      const int idxp = prow * 16 + ((ks * 4 + quad) ^ (m0 & 15));
      const bf16x8v pa = *reinterpret_cast<const bf16x8v*>(smem + idxp * 16);
#pragma unroll
      for (int ni = 0; ni < 8; ni++) {
        const int dv = ni * 16 + m0;
        const int idxv = dv * 16 + ((ks * 4 + quad) ^ (dv & 15));
        const bf16x8v vb = *reinterpret_cast<const bf16x8v*>(smem + 36864 + idxv * 16);
        O[ni] = __builtin_amdgcn_mfma_f32_16x16x32_bf16(pa, vb, O[ni], 0, 0, 0);
      }
    }
    __syncthreads();  // PV reads done before next iter's staging
  }

  float lO[4];
#pragma unroll
  for (int r = 0; r < 4; r++) lO[r] = 1.f / __shfl(lrow, quad * 4 + r, 16);
#pragma unroll
  for (int ni = 0; ni < 8; ni++)
#pragma unroll
    for (int r = 0; r < 4; r++)
      attn[((long)tile * 64 + w * 16 + quad * 4 + r) * HV + h * DVC + ni * 16 + m0] =
          __float2bfloat16(O[ni][r] * lO[r]);
}

// ---------------- small kernels ----------------
__device__ __forceinline__ float tofl(float x) { return x; }
__device__ __forceinline__ float tofl(bf16 x) { return __bfloat162float(x); }

template <typename TIN>
__global__ __launch_bounds__(256) void transpose_cast(const TIN* __restrict__ in,
                                                      bf16* __restrict__ out,
                                                      int inStride, int outStride) {
  __shared__ float t[32][33];
  const int bx = blockIdx.x * 32, by = blockIdx.y * 32;
  const int tx = threadIdx.x, ty = threadIdx.y;
#pragma unroll
  for (int j = 0; j < 32; j += 8)
    t[ty + j][tx] = tofl(in[(long)(by + ty + j) * inStride + bx + tx]);
  __syncthreads();
#pragma unroll
  for (int j = 0; j < 32; j += 8)
    out[(long)(bx + ty + j) * outStride + by + tx] = __float2bfloat16(t[tx][ty + j]);
}

struct TPar { const float* src; bf16* dst; int C; int R; int gw; int nblk; };

// six independent fp32->bf16 transposes in one launch
__global__ __launch_bounds__(256) void transpose6(TPar a, TPar b, TPar c,
                                                  TPar d, TPar e, TPar f) {
  int blk = blockIdx.x;
  TPar p;
  if (blk < a.nblk) p = a;
  else { blk -= a.nblk;
  if (blk < b.nblk) p = b;
  else { blk -= b.nblk;
  if (blk < c.nblk) p = c;
  else { blk -= c.nblk;
  if (blk < d.nblk) p = d;
  else { blk -= d.nblk;
  if (blk < e.nblk) p = e;
  else { blk -= e.nblk; p = f; } } } } }
  const int bx = (blk % p.gw) * 32, by = (blk / p.gw) * 32;
  __shared__ float t[32][33];
  const int tx = threadIdx.x, ty = threadIdx.y;
#pragma unroll
  for (int j = 0; j < 32; j += 8)
    t[ty + j][tx] = p.src[(long)(by + ty + j) * p.C + bx + tx];
  __syncthreads();
#pragma unroll
  for (int j = 0; j < 32; j += 8)
    p.dst[(long)(bx + ty + j) * p.R + by + tx] = __float2bfloat16(t[tx][ty + j]);
}

__global__ __launch_bounds__(256) void cast_f32_bf16(const float* __restrict__ in,
                                                     bf16* __restrict__ out, int n4) {
  int i = blockIdx.x * 256 + threadIdx.x;
  if (i < n4) {
    const float4 v = ((const float4*)in)[i];
    out[i * 4 + 0] = __float2bfloat16(v.x);
    out[i * 4 + 1] = __float2bfloat16(v.y);
    out[i * 4 + 2] = __float2bfloat16(v.z);
    out[i * 4 + 3] = __float2bfloat16(v.w);
  }
}

__global__ __launch_bounds__(256) void rope_qk(bf16* __restrict__ q, bf16* __restrict__ k) {
  const int idx = blockIdx.x * 256 + threadIdx.x;  // SEQ*NHEADS*32 threads
  const int i = idx & 31;
  const int h = (idx >> 5) & 15;
  const int l = idx >> 9;
  const float inv = powf(10000.f, -(float)i * (1.f / 32.f));
  float s, c;
  sincosf((float)l * inv, &s, &c);
  const long qb = (long)l * HQK + h * DQKC + 128;
  const long kb = (long)l * NKV + h * DQKC + 128;
  {
    float x0 = __bfloat162float(q[qb + i]);
    float x1 = __bfloat162float(q[qb + i + 32]);
    q[qb + i] = __float2bfloat16(x0 * c - x1 * s);
    q[qb + i + 32] = __float2bfloat16(x1 * c + x0 * s);
  }
  {
    float x0 = __bfloat162float(k[kb + i]);
    float x1 = __bfloat162float(k[kb + i + 32]);
    k[kb + i] = __float2bfloat16(x0 * c - x1 * s);
    k[kb + i + 32] = __float2bfloat16(x1 * c + x0 * s);
  }
}

extern "C" void kernel_launch(void* const* d_in, const int* in_sizes, int n_in,
                              void* d_out, int out_size, void* d_ws, size_t ws_size,
                              hipStream_t stream) {
  const float* hs      = (const float*)d_in[0];
  // d_in[1] attention_mask: exact causal mask; applied analytically.
  const float* Wq_down = (const float*)d_in[2];
  const float* Wq_up   = (const float*)d_in[3];
  const float* Wkv_down= (const float*)d_in[4];
  const float* Wk_up   = (const float*)d_in[5];
  const float* Wv_up   = (const float*)d_in[6];
  const float* Wo      = (const float*)d_in[7];

  char* p = (char*)d_ws;
  auto alloc = [&](long elems) {
    bf16* r = (bf16*)p;
    p += ((elems * 2 + 255) / 256) * 256;
    return r;
  };
  bf16* hsb   = alloc((long)SEQ * DMODEL);
  bf16* W1T   = alloc((long)NDOWN * DMODEL);
  bf16* WquT  = alloc((long)HQK * DQC);
  bf16* WkvuT = alloc((long)NKV * DCC);
  bf16* WoT   = alloc((long)DMODEL * HV);
  bf16* qdc   = alloc((long)SEQ * NDOWN);
  bf16* qf    = alloc((long)SEQ * HQK);
  bf16* kvf   = alloc((long)SEQ * NKV);
  bf16* vT    = alloc((long)HV * SEQ);
  bf16* attn  = alloc((long)SEQ * HV);

  const float scale = 0.07216878364870323f;  // 1/sqrt(192), folded into q

  const dim3 b256(256);
  const dim3 tb(32, 8);
  cast_f32_bf16<<<dim3(SEQ * DMODEL / 4 / 256), b256, 0, stream>>>(hs, hsb, SEQ * DMODEL / 4);

  TPar ta{Wq_down,  W1T,                      DQC,    DMODEL, DQC / 32,    (DQC / 32) * (DMODEL / 32)};
  TPar tb2{Wkv_down, W1T + (long)DQC * DMODEL, DCC,    DMODEL, DCC / 32,    (DCC / 32) * (DMODEL / 32)};
  TPar tc{Wq_up,    WquT,                     HQK,    DQC,    HQK / 32,    (HQK / 32) * (DQC / 32)};
  TPar td{Wk_up,    WkvuT,                    HQK,    DCC,    HQK / 32,    (HQK / 32) * (DCC / 32)};
  TPar te{Wv_up,    WkvuT + (long)HQK * DCC,  HV,     DCC,    HV / 32,     (HV / 32) * (DCC / 32)};
  TPar tf{Wo,       WoT,                      DMODEL, HV,     DMODEL / 32, (DMODEL / 32) * (HV / 32)};
  const int tblk = ta.nblk + tb2.nblk + tc.nblk + td.nblk + te.nblk + tf.nblk;
  transpose6<<<dim3(tblk), tb, 0, stream>>>(ta, tb2, tc, td, te, tf);

  // fused down-projection: [qd | ckv] = hsb @ [Wq_down | Wkv_down]
  gemm64<<<dim3(NDOWN / 128, SEQ / 64), b256, 0, stream>>>(
      hsb, DMODEL, W1T, DMODEL, qdc, NDOWN, DMODEL, 1.f, 0);

  // q up (scale folded) + fused k/v up, one launch
  gemm_dual<<<dim3(HQK / 128 + NKV / 128, SEQ / 64), b256, 0, stream>>>(
      qdc, NDOWN, WquT, DQC, qf, HQK, DQC, scale, HQK / 128,
      qdc + DQC, NDOWN, WkvuT, DCC, kvf, NKV, DCC);

  rope_qk<<<dim3(SEQ * NHEADS * 32 / 256), b256, 0, stream>>>(qf, kvf);
  transpose_cast<bf16><<<dim3(HV / 32, SEQ / 32), tb, 0, stream>>>(kvf + HQK, vT, NKV, SEQ);

  // fused attention
  flash_attn<<<dim3(512), b256, 0, stream>>>(qf, kvf, vT, attn);

  // output projection (fp32 out)
  gemm64<<<dim3(DMODEL / 128, SEQ / 64), b256, 0, stream>>>(
      attn, HV, WoT, HV, d_out, DMODEL, HV, 1.f, 1);
}